// Round 7
// baseline (1974.429 us; speedup 1.0000x reference)
//
#include <hip/hip_runtime.h>
#include <math.h>

// NeuroSAT, MI355X. Round 7: r5 (proven-correct sc1 coherence, blockIdx
// groups) + full-line coalesced sc1 writes + no own-row reload.
//  - r6 lesson: physical-XCD ticketing deadlocks on uneven block->XCD
//    distribution. Reverted to blockIdx grouping (r4/r5 proven).
//  - r5 lesson: 777MB/dispatch write traffic = 6.6x amplification from
//    16B-scattered sc1 stores. Now all comm writes are staged in LDS and
//    issued as wave-contiguous full-line stores (out_g via hbuf, chg via LM).
//  - Own rows stay in LDS (hbuf->buf copy); only the pair block's 128B piece
//    is re-read from out_g per step.
//  - Arithmetic identical to r3-r5: absmax must be exactly 0.01367188.

#define NV2_   800
#define NC_    440
#define KK_    12
#define NPG_   1240
#define NLIT_  12800
#define NCLS_  7040
#define NE_    84480
#define NN_    19840
#define STEPS_ 23
#define GRP_   8
#define LITB_G 26
#define CLSB_G 6
#define BLK_G  32
#define NBLK_  256
#define PHSTR_ 16
#define SMEM_BYTES 151552

__device__ __forceinline__ float sigmf(float x) { return 1.0f / (1.0f + __expf(-x)); }
__device__ __forceinline__ float tanhf_(float x) { return 1.0f - 2.0f / (__expf(2.0f * x) + 1.0f); }

// device-coherent (sc1) helpers: bypass L1/L2, LLC is the common point
__device__ __forceinline__ float ldg_sc(const float* p)
{
    return __hip_atomic_load(p, __ATOMIC_RELAXED, __HIP_MEMORY_SCOPE_AGENT);
}
__device__ __forceinline__ unsigned long long ldg_sc8(const float* p)
{
    return __hip_atomic_load((const unsigned long long*)p, __ATOMIC_RELAXED, __HIP_MEMORY_SCOPE_AGENT);
}
__device__ __forceinline__ void stg_sc2(float* p, float a, float b)
{
    union { float f[2]; unsigned long long u; } x;
    x.f[0] = a; x.f[1] = b;
    __hip_atomic_store((unsigned long long*)p, x.u, __ATOMIC_RELAXED, __HIP_MEMORY_SCOPE_AGENT);
}

// ---------------- setup kernels (unchanged) ----------------

__global__ __launch_bounds__(256) void collapse_k(
    const float* lm1, const float* lm1b, const float* lm2, const float* lm2b, const float* lm3, const float* lm3b,
    const float* cm1, const float* cm1b, const float* cm2, const float* cm2b, const float* cm3, const float* cm3b,
    const float* lv1, const float* lv1b, const float* lv2, const float* lv2b, const float* lv3, const float* lv3b,
    float* Wl, float* bl, float* Wc, float* bc, float* Wv, float* bv)
{
    __shared__ float T[4096];
    __shared__ float ub[64];
    __shared__ float t3[64];
    int r = blockIdx.x, t = threadIdx.x;
    if (r < 2) {
        const float* w1 = r ? cm1 : lm1; const float* b1 = r ? cm1b : lm1b;
        const float* w2 = r ? cm2 : lm2; const float* b2 = r ? cm2b : lm2b;
        const float* w3 = r ? cm3 : lm3; const float* b3 = r ? cm3b : lm3b;
        float* W = r ? Wc : Wl;  float* bb = r ? bc : bl;
        for (int idx = t; idx < 4096; idx += 256) {
            int i = idx >> 6, j = idx & 63;
            float s = 0.f;
            for (int k = 0; k < 64; ++k) s += w1[i * 64 + k] * w2[k * 64 + j];
            T[idx] = s;
        }
        if (t < 64) {
            float s = 0.f;
            for (int k = 0; k < 64; ++k) s += b1[k] * w2[k * 64 + t];
            ub[t] = s + b2[t];
        }
        __syncthreads();
        for (int idx = t; idx < 4096; idx += 256) {
            int i = idx >> 6, j = idx & 63;
            float s = 0.f;
            for (int k = 0; k < 64; ++k) s += T[i * 64 + k] * w3[k * 64 + j];
            W[idx] = s;
        }
        if (t < 64) {
            float s = 0.f;
            for (int k = 0; k < 64; ++k) s += ub[k] * w3[k * 64 + t];
            bb[t] = s + b3[t];
        }
    } else {
        if (t < 64) {
            float s = 0.f;
            for (int j = 0; j < 64; ++j) s += lv2[t * 64 + j] * lv3[j];
            t3[t] = s;
            float s2 = 0.f;
            for (int k = 0; k < 64; ++k) s2 += lv1b[k] * lv2[k * 64 + t];
            ub[t] = s2 + lv2b[t];
        }
        __syncthreads();
        if (t < 64) {
            float s = 0.f;
            for (int k = 0; k < 64; ++k) s += lv1[t * 64 + k] * t3[k];
            Wv[t] = s;
        }
        if (t == 0) {
            float s = 0.f;
            for (int j = 0; j < 64; ++j) s += ub[j] * lv3[j];
            bv[0] = s + lv3b[0];
        }
    }
}

__global__ __launch_bounds__(256) void fold_k(
    const float* Wl, const float* bl, const float* Wc, const float* bc,
    const float* lwih, const float* lbih, const float* lbhh,
    const float* cwih, const float* cbih, const float* cbhh,
    float* Wfl, float* bfl, float* Bl, float* Wfc, float* Bc)
{
    int j = threadIdx.x;
    if (blockIdx.x == 0) {
        for (int i = 0; i < 64; ++i) {
            float s = 0.f;
            for (int m = 0; m < 64; ++m) s += Wc[i * 64 + m] * lwih[(64 + m) * 256 + j];
            Wfl[i * 256 + j] = s;
        }
        float s = 0.f;
        for (int m = 0; m < 64; ++m) s += bc[m] * lwih[(64 + m) * 256 + j];
        bfl[j] = s;
        Bl[j] = lbih[j] + lbhh[j];
    } else {
        for (int i = 0; i < 64; ++i) {
            float s = 0.f;
            for (int m = 0; m < 64; ++m) s += Wl[i * 64 + m] * cwih[m * 256 + j];
            Wfc[i * 256 + j] = s;
        }
        float s = 0.f;
        for (int m = 0; m < 64; ++m) s += bl[m] * cwih[m * 256 + j];
        Bc[j] = cbih[j] + cbhh[j] + 13.f * s;
    }
}

__global__ __launch_bounds__(256) void init_k(
    const float* x, const float* liw, const float* lib, const float* ciw, const float* cib,
    float* out0, float* outc)
{
    int t = blockIdx.x * 256 + threadIdx.x;
    if (t >= NN_ * 64) return;
    int node = t >> 6, j = t & 63;
    int b = node / NPG_;
    int i = node - b * NPG_;
    float x0 = x[node * 2 + 0], x1 = x[node * 2 + 1];
    if (i < NV2_) {
        int sp = (i < 400) ? 2 * i : 2 * (i - 400) + 1;
        out0[(size_t)(b * NV2_ + sp) * 64 + j] = x0 * liw[j] + x1 * liw[64 + j] + lib[j];
    } else {
        outc[(size_t)(b * NC_ + (i - NV2_)) * 64 + j] = x0 * ciw[j] + x1 * ciw[64 + j] + cib[j];
    }
}

__global__ __launch_bounds__(256) void econv_k(const int* ei, int* llits, int* cnt)
{
    int e = blockIdx.x * 256 + threadIdx.x;
    if (e >= NE_) return;
    int g = ei[e];
    int b = g / NPG_;
    int i = g - b * NPG_;
    int sp = (i < 400) ? 2 * i : 2 * (i - 400) + 1;
    int L = b * NV2_ + sp;
    llits[e] = L;
    atomicAdd(cnt + L, 1);
}

__global__ __launch_bounds__(1024) void scan_k(const int* cnt, int* rowptr, int* cursor)
{
    __shared__ int sums[1024];
    int t = threadIdx.x;
    int i0 = t * 13;
    int i1 = i0 + 13; if (i1 > NLIT_) i1 = NLIT_; if (i0 > NLIT_) i0 = NLIT_;
    int s = 0;
    for (int i = i0; i < i1; ++i) s += cnt[i];
    sums[t] = s;
    __syncthreads();
    for (int off = 1; off < 1024; off <<= 1) {
        int v = (t >= off) ? sums[t - off] : 0;
        __syncthreads();
        sums[t] += v;
        __syncthreads();
    }
    int run = sums[t] - s;
    for (int i = i0; i < i1; ++i) { rowptr[i] = run; cursor[i] = run; run += cnt[i]; }
    if (t == 1023) rowptr[NLIT_] = sums[1023];
}

__global__ __launch_bounds__(256) void fill_k(const int* llits, int* cursor, int* col)
{
    int e = blockIdx.x * 256 + threadIdx.x;
    if (e >= NE_) return;
    int pos = atomicAdd(cursor + llits[e], 1);
    col[pos] = e / KK_;
}

// ---------------- persistent fused kernel ----------------

struct KArgs {
    float* out_g; float* outc0; float* chg;
    const int* llits; const int* rowptr; const int* col;
    const float* Wfl; const float* bfl; const float* Bl;
    const float* Wfc; const float* Bc;
    const float* lwih; const float* lwhh; const float* cwhh;
    const float* Wv; const float* bv;
    float* vout; int* bar;
};

__device__ __forceinline__ void bar_arrive(int* barg, int ph)
{
    __syncthreads();   // drains this block's vm/lgkm before t0 releases
    if (threadIdx.x == 0)
        __hip_atomic_fetch_add(barg + ph * PHSTR_, 1, __ATOMIC_RELEASE, __HIP_MEMORY_SCOPE_AGENT);
}

__device__ __forceinline__ void bar_wait(int* barg, int ph)
{
    if (threadIdx.x == 0) {
        while (__hip_atomic_load(barg + ph * PHSTR_, __ATOMIC_RELAXED, __HIP_MEMORY_SCOPE_AGENT) < BLK_G)
            __builtin_amdgcn_s_sleep(1);
    }
    asm volatile("" ::: "memory");
    __syncthreads();
}

// acc[g*4+q] += sum_k row[k] * W[k*WC + g*GS + uc4 + q]   (weights: LDS broadcast)
template<int WC, int GS>
__device__ __forceinline__ void gemm16(const float* __restrict__ row,
                                       const float* __restrict__ W,
                                       int uc4, float* acc)
{
    const float4* p = (const float4*)row;
#pragma unroll 4
    for (int k4 = 0; k4 < 16; ++k4) {
        float4 v = p[k4];
        const float* wk = W + (k4 * 4) * WC + uc4;
#pragma unroll
        for (int e = 0; e < 4; ++e) {
            float u = (e == 0) ? v.x : (e == 1) ? v.y : (e == 2) ? v.z : v.w;
            const float* wb = wk + e * WC;
#pragma unroll
            for (int g = 0; g < 4; ++g) {
                float4 w = *(const float4*)(wb + g * GS);
                acc[g * 4 + 0] = fmaf(u, w.x, acc[g * 4 + 0]);
                acc[g * 4 + 1] = fmaf(u, w.y, acc[g * 4 + 1]);
                acc[g * 4 + 2] = fmaf(u, w.z, acc[g * 4 + 2]);
                acc[g * 4 + 3] = fmaf(u, w.w, acc[g * 4 + 3]);
            }
        }
    }
}

__device__ __forceinline__ void cell4(const float* acc, float* c, float* h)
{
#pragma unroll
    for (int q = 0; q < 4; ++q) {
        float iv = sigmf(acc[q]);
        float fv = sigmf(acc[4 + q]);
        float gv = tanhf_(acc[8 + q]);
        float ov = sigmf(acc[12 + q]);
        float c2 = fv * c[q] + iv * gv;
        c[q] = c2;
        h[q] = ov * tanhf_(c2);
    }
}

__global__ __launch_bounds__(1024) void fused_k(KArgs a)
{
    extern __shared__ float sm[];
    const int tid = threadIdx.x;
    const int lane = tid & 63;
    const int wv = tid >> 6;                 // 0..15
    const int grp = blockIdx.x & 7;
    const int idx = blockIdx.x >> 3;         // role within group: 0..31
    int* barg = a.bar + grp * 48 * PHSTR_;

    if (idx < LITB_G) {
        // ======== literal block: <=128 rows x unit-half (32 units) ========
        const int rowgrp = idx >> 1;
        const int half = idx & 1;
        const int U0 = half * 32;
        const int OC = U0 ^ 32;            // other half's unit base
        const int Lb = grp * 1600 + rowgrp * 128;
        const int nrows = (rowgrp < 12) ? 128 : 64;
        float* wih_s = sm;                 // 64x128 (unit-half slice)
        float* whh_s = sm + 8192;
        float* wfl_s = sm + 16384;
        float* buf   = sm + 24576;         // 128 rows x stride 68 (full 64-col rows)
        float* hbuf  = sm + 33280;         // 128 rows x stride 36 (own 32-col piece)

        for (int i2 = tid; i2 < 8192; i2 += 1024) {
            int k = i2 >> 7, r = i2 & 127, gg = r >> 5, j = r & 31;
            int src = k * 256 + gg * 64 + U0 + j;
            wih_s[i2] = a.lwih[src];
            whh_s[i2] = a.lwhh[src];
            wfl_s[i2] = a.Wfl[src];
        }

        const int rh = wv >> 3, uc = wv & 7, uc4 = uc * 4;
        const int lr = rh * 64 + lane;
        const bool vrow = (lr < nrows);
        const int R = Lb + (vrow ? lr : 0);
        const int unit0 = U0 + uc4;
        const float degf = 1.f + (float)(a.rowptr[R + 1] - a.rowptr[R]);

        float bias[16];
#pragma unroll
        for (int g = 0; g < 4; ++g)
#pragma unroll
            for (int q = 0; q < 4; ++q)
                bias[g * 4 + q] = a.Bl[g * 64 + unit0 + q] + degf * a.bfl[g * 64 + unit0 + q];

        float lc4[4] = {0.f, 0.f, 0.f, 0.f};

        // thread-mapped piece indices: trow in [0,128), tc4 in {0,4,...,28}
        const int trow = tid >> 3;
        const int tc4 = (tid & 7) << 2;
        __syncthreads();

        for (int step = 0; step < STEPS_; ++step) {
            // slot1: assemble buf = out(step) full rows.
            //  own piece: hbuf (LDS) [step>0] or out_g [step 0]
            //  other piece: pair block's out_g write (sc1)
            if (trow < nrows) {
                const float* sp_ = a.out_g + (size_t)(Lb + trow) * 64;
                if (step == 0) {
                    union { unsigned long long u[2]; float f[4]; } d;
                    d.u[0] = ldg_sc8(sp_ + U0 + tc4);
                    d.u[1] = ldg_sc8(sp_ + U0 + tc4 + 2);
                    *(float4*)(buf + trow * 68 + U0 + tc4) = *(float4*)d.f;
                } else {
                    *(float4*)(buf + trow * 68 + U0 + tc4) = *(float4*)(hbuf + trow * 36 + tc4);
                }
                union { unsigned long long u[2]; float f[4]; } d2;
                d2.u[0] = ldg_sc8(sp_ + OC + tc4);
                d2.u[1] = ldg_sc8(sp_ + OC + tc4 + 2);
                *(float4*)(buf + trow * 68 + OC + tc4) = *(float4*)d2.f;
            }
            __syncthreads();
            float acc[16];
#pragma unroll
            for (int i = 0; i < 16; ++i) acc[i] = bias[i];
            gemm16<128, 32>(buf + (size_t)(lr ^ 1) * 68, wih_s, uc4, acc);     // out[flip] @ wih_top
            if (step) gemm16<128, 32>(buf + (size_t)lr * 68, whh_s, uc4, acc); // lh @ whh
            bar_arrive(barg, 2 * step);        // S2 arrive (out_g reads done)
            bar_wait(barg, 2 * step);          // S2 wait: chg(step) ready
            // slot2: gather clause h, folded GEMM, cell
            for (int s8 = 0; s8 < 8; ++s8) {
                int srow = wv * 8 + s8;
                if (srow >= nrows) continue;
                int l = Lb + srow;
                int e = a.rowptr[l], eE = a.rowptr[l + 1];
                float v = buf[srow * 68 + lane];
                for (; e + 4 <= eE; e += 4) {
                    float t0 = ldg_sc(a.chg + (size_t)a.col[e    ] * 64 + lane);
                    float t1 = ldg_sc(a.chg + (size_t)a.col[e + 1] * 64 + lane);
                    float t2 = ldg_sc(a.chg + (size_t)a.col[e + 2] * 64 + lane);
                    float t3 = ldg_sc(a.chg + (size_t)a.col[e + 3] * 64 + lane);
                    v += t0 + t1 + t2 + t3;
                }
                for (; e < eE; ++e) v += ldg_sc(a.chg + (size_t)a.col[e] * 64 + lane);
                buf[srow * 68 + lane] = v;
            }
            __syncthreads();
            gemm16<128, 32>(buf + (size_t)lr * 68, wfl_s, uc4, acc);
            float h2[4];
            cell4(acc, lc4, h2);
            // stage h into hbuf (full own piece), then coalesced sc1 store
#pragma unroll
            for (int q = 0; q < 4; ++q) hbuf[lr * 36 + uc4 + q] = h2[q];
            __syncthreads();
            if (trow < nrows) {
                float* dp = a.out_g + (size_t)(Lb + trow) * 64 + U0 + tc4;
                const float* hp = hbuf + trow * 36 + tc4;
                stg_sc2(dp,     hp[0], hp[1]);
                stg_sc2(dp + 2, hp[2], hp[3]);
            }
            if (step < STEPS_ - 1) {
                bar_arrive(barg, 2 * step + 1);    // S1 arrive (out_g written, chg reads done)
                bar_wait(barg, 2 * step + 1);
            } else {
                // vote epilogue
                float p = h2[0] * a.Wv[unit0] + h2[1] * a.Wv[unit0 + 1]
                        + h2[2] * a.Wv[unit0 + 2] + h2[3] * a.Wv[unit0 + 3];
                __syncthreads();
                if (vrow) buf[lr * 8 + uc] = p;
                __syncthreads();
                if (uc == 0 && vrow) {
                    float v = (half == 0) ? a.bv[0] : 0.f;
#pragma unroll
                    for (int w = 0; w < 8; ++w) v += buf[lr * 8 + w];
                    int b = R / NV2_;
                    int pos = R - b * NV2_;
                    int pi = (pos >> 1) + (pos & 1) * 400;   // undo pair-interleave
                    atomicAdd(a.vout + b * NPG_ + pi, v);
                }
            }
        }
    } else {
        // ======== clause block: ~147 rows (3 subgroups of <=64), full 64 units ========
        const int ci = idx - LITB_G;                         // 0..5
        const int rows = (ci < 4) ? 147 : 146;               // 880 rows per group
        const int c0 = grp * 880 + ci * 147 - ((ci > 4) ? (ci - 4) : 0);
        float* wfc_s  = sm;             // 64x256
        float* cwhh_s = sm + 16384;     // 64x256
        float* LM     = sm + 32768;     // 64 rows x stride 68
        for (int i2 = tid; i2 < 16384; i2 += 1024) {
            wfc_s[i2]  = a.Wfc[i2];
            cwhh_s[i2] = a.cwhh[i2];
        }
        const int u0 = wv * 4;          // this wave's 4 units
        float bc16[16];
#pragma unroll
        for (int g = 0; g < 4; ++g)
#pragma unroll
            for (int q = 0; q < 4; ++q) bc16[g * 4 + q] = a.Bc[g * 64 + u0 + q];
        float cc_r[3][4] = {};
        float acc2[3][16] = {};
        // thread-mapped store indices: srw in [0,64), sc4 in {0,4,...,60}
        const int srw = tid >> 4;
        const int sc4 = (tid & 15) << 2;
        __syncthreads();

        for (int step = 0; step < STEPS_; ++step) {
            float ch_r[3][4];
#pragma unroll 1
            for (int sg = 0; sg < 3; ++sg) {
                const int r0 = sg * 64;
                const int cnt = (rows - r0 < 64) ? (rows - r0) : 64;
                // gather lmsg = clause_out + sum of 12 literal outs
                for (int s4 = 0; s4 < 4; ++s4) {
                    int srow = wv * 4 + s4;
                    if (srow < cnt) {
                        int c = c0 + r0 + srow;
                        float v = step ? ldg_sc(a.chg + (size_t)c * 64 + lane)
                                       : a.outc0[(size_t)c * 64 + lane];
                        const int* lp = a.llits + c * KK_;
#pragma unroll
                        for (int k = 0; k < KK_; ++k)
                            v += ldg_sc(a.out_g + (size_t)lp[k] * 64 + lane);
                        LM[srow * 68 + lane] = v;
                    }
                }
                __syncthreads();
                float acc[16];
#pragma unroll
                for (int i = 0; i < 16; ++i) acc[i] = bc16[i] + acc2[sg][i];
                gemm16<256, 64>(LM + (size_t)lane * 68, wfc_s, u0, acc);
                cell4(acc, cc_r[sg], ch_r[sg]);
                __syncthreads();    // all LM gather reads done
                // stage full ch rows into LM, then coalesced sc1 store of chg
#pragma unroll
                for (int q = 0; q < 4; ++q) LM[lane * 68 + u0 + q] = ch_r[sg][q];
                __syncthreads();
                if (srw < cnt) {
                    float* dp = a.chg + (size_t)(c0 + r0 + srw) * 64 + sc4;
                    const float* hp = LM + srw * 68 + sc4;
                    stg_sc2(dp,     hp[0], hp[1]);
                    stg_sc2(dp + 2, hp[2], hp[3]);
                }
                __syncthreads();    // LM free for next subgroup's gather
            }
            bar_arrive(barg, 2 * step);    // S2 arrive (chg written); clause skips S2 wait
            if (step < STEPS_ - 1) {
                // precompute ch(step) @ cwhh for next step while lit does slot2
#pragma unroll 1
                for (int sg = 0; sg < 3; ++sg) {
                    *(float4*)(LM + (size_t)lane * 68 + u0) =
                        make_float4(ch_r[sg][0], ch_r[sg][1], ch_r[sg][2], ch_r[sg][3]);
                    __syncthreads();
#pragma unroll
                    for (int i = 0; i < 16; ++i) acc2[sg][i] = 0.f;
                    gemm16<256, 64>(LM + (size_t)lane * 68, cwhh_s, u0, acc2[sg]);
                    __syncthreads();
                }
                bar_arrive(barg, 2 * step + 1);    // S1 arrive
                bar_wait(barg, 2 * step + 1);      // S1 wait: out_g(step+1) ready
            }
        }
    }
}

// ---------------- host ----------------

extern "C" void kernel_launch(void* const* d_in, const int* in_sizes, int n_in,
                              void* d_out, int out_size, void* d_ws, size_t ws_size,
                              hipStream_t stream)
{
    (void)in_sizes; (void)n_in; (void)out_size; (void)ws_size;
    const float* x    = (const float*)d_in[0];
    const int*   ei   = (const int*)d_in[2];
    const float* liw  = (const float*)d_in[4];
    const float* lib  = (const float*)d_in[5];
    const float* ciw  = (const float*)d_in[6];
    const float* cib  = (const float*)d_in[7];
    const float* lm1  = (const float*)d_in[8];
    const float* lm1b = (const float*)d_in[9];
    const float* lm2  = (const float*)d_in[10];
    const float* lm2b = (const float*)d_in[11];
    const float* lm3  = (const float*)d_in[12];
    const float* lm3b = (const float*)d_in[13];
    const float* cm1  = (const float*)d_in[14];
    const float* cm1b = (const float*)d_in[15];
    const float* cm2  = (const float*)d_in[16];
    const float* cm2b = (const float*)d_in[17];
    const float* cm3  = (const float*)d_in[18];
    const float* cm3b = (const float*)d_in[19];
    const float* lu_wih = (const float*)d_in[20];
    const float* lu_whh = (const float*)d_in[21];
    const float* lu_bih = (const float*)d_in[22];
    const float* lu_bhh = (const float*)d_in[23];
    const float* cu_wih = (const float*)d_in[24];
    const float* cu_whh = (const float*)d_in[25];
    const float* cu_bih = (const float*)d_in[26];
    const float* cu_bhh = (const float*)d_in[27];
    const float* lv1  = (const float*)d_in[28];
    const float* lv1b = (const float*)d_in[29];
    const float* lv2  = (const float*)d_in[30];
    const float* lv2b = (const float*)d_in[31];
    const float* lv3  = (const float*)d_in[32];
    const float* lv3b = (const float*)d_in[33];

    float* F = (float*)d_ws;
    size_t o = 0;
    auto A = [&](size_t n) { float* p = F + o; o += n; return p; };
    float* out_g = A((size_t)NLIT_ * 64);
    float* outc0 = A((size_t)NCLS_ * 64);
    float* chg   = A((size_t)NCLS_ * 64);
    float* Wl    = A(4096);
    float* Wc    = A(4096);
    float* bl    = A(64);
    float* bc    = A(64);
    float* Wv    = A(64);
    float* bv    = A(16);
    float* Wfl   = A(64 * 256);
    float* bfl   = A(256);
    float* Bl    = A(256);
    float* Wfc   = A(64 * 256);
    float* Bc    = A(256);
    int* I = (int*)(F + o);
    int* llits  = I; I += NE_;
    int* rowptr = I; I += 12804;
    int* cursor = I; I += NLIT_;
    int* colA   = I; I += NE_;
    int* cnt    = I; I += NLIT_;
    int* bar    = I; I += GRP_ * 48 * PHSTR_;

    hipMemsetAsync(cnt, 0, NLIT_ * sizeof(int), stream);
    hipMemsetAsync(bar, 0, GRP_ * 48 * PHSTR_ * sizeof(int), stream);
    hipMemsetAsync(d_out, 0, (size_t)NN_ * sizeof(float), stream);

    collapse_k<<<3, 256, 0, stream>>>(lm1, lm1b, lm2, lm2b, lm3, lm3b,
                                      cm1, cm1b, cm2, cm2b, cm3, cm3b,
                                      lv1, lv1b, lv2, lv2b, lv3, lv3b,
                                      Wl, bl, Wc, bc, Wv, bv);
    fold_k<<<2, 256, 0, stream>>>(Wl, bl, Wc, bc,
                                  lu_wih, lu_bih, lu_bhh,
                                  cu_wih, cu_bih, cu_bhh,
                                  Wfl, bfl, Bl, Wfc, Bc);
    init_k<<<(NN_ * 64 + 255) / 256, 256, 0, stream>>>(x, liw, lib, ciw, cib, out_g, outc0);
    econv_k<<<NE_ / 256, 256, 0, stream>>>(ei, llits, cnt);
    scan_k<<<1, 1024, 0, stream>>>(cnt, rowptr, cursor);
    fill_k<<<NE_ / 256, 256, 0, stream>>>(llits, cursor, colA);

    KArgs ka;
    ka.out_g = out_g; ka.outc0 = outc0; ka.chg = chg;
    ka.llits = llits; ka.rowptr = rowptr; ka.col = colA;
    ka.Wfl = Wfl; ka.bfl = bfl; ka.Bl = Bl; ka.Wfc = Wfc; ka.Bc = Bc;
    ka.lwih = lu_wih; ka.lwhh = lu_whh; ka.cwhh = cu_whh;
    ka.Wv = Wv; ka.bv = bv;
    ka.vout = (float*)d_out;
    ka.bar = bar;

    void* params[] = { &ka };
    hipError_t err = hipLaunchCooperativeKernel((void*)fused_k, dim3(NBLK_), dim3(1024),
                                                params, SMEM_BYTES, stream);
    if (err != hipSuccess) {
        fused_k<<<NBLK_, 1024, SMEM_BYTES, stream>>>(ka);
    }
}

// Round 9
// 1904.947 us; speedup vs baseline: 1.0365x; 1.0365x over previous
//
#include <hip/hip_runtime.h>
#include <math.h>

// NeuroSAT, MI355X. Round 9: r4-proven coherence + full-line stores +
// minimal-participation barriers.
//  - r8 refuted dirty-L2 sharing: groups are NOT same-XCD; comm must transit
//    LLC via RELEASE(writeback)/ACQUIRE(inv). r4's FETCH=12.5MB was LLC
//    absorption (FETCH counts HBM only), not dirty-line sharing.
//  - Write amplification (r4 448MB, r7 549MB) was store DENSITY, not the
//    protocol: 16B-per-lane @ 256B stride = 4x line padding. Fix: stage in
//    LDS (hbuf/LM), store full 64B-line-dense float4 (r7 mapping) with PLAIN
//    cached stores; dirty L2 = true 5.1MB/step -> release drain ~1us.
//  - Barriers: S2 = clause-arrive-only (target 6, RELEASE: publishes chg);
//    S1 = lit-arrive-only (target 26, RELEASE: publishes out_g + certifies
//    chg reads). All waits are ACQUIRE spin-loads. Fewer atomics, fewer
//    writeback drains (2 releases/step total).
//  - Gathers batch 8 loads before summing (latency MLP).
//  - Arithmetic identical to r3-r7: absmax must be exactly 0.01367188.

#define NV2_   800
#define NC_    440
#define KK_    12
#define NPG_   1240
#define NLIT_  12800
#define NCLS_  7040
#define NE_    84480
#define NN_    19840
#define STEPS_ 23
#define GRP_   8
#define LITB_G 26
#define CLSB_G 6
#define BLK_G  32
#define NBLK_  256
#define PHSTR_ 16
#define SMEM_BYTES 151552

__device__ __forceinline__ float sigmf(float x) { return 1.0f / (1.0f + __expf(-x)); }
__device__ __forceinline__ float tanhf_(float x) { return 1.0f - 2.0f / (__expf(2.0f * x) + 1.0f); }

// ---------------- setup kernels (unchanged) ----------------

__global__ __launch_bounds__(256) void collapse_k(
    const float* lm1, const float* lm1b, const float* lm2, const float* lm2b, const float* lm3, const float* lm3b,
    const float* cm1, const float* cm1b, const float* cm2, const float* cm2b, const float* cm3, const float* cm3b,
    const float* lv1, const float* lv1b, const float* lv2, const float* lv2b, const float* lv3, const float* lv3b,
    float* Wl, float* bl, float* Wc, float* bc, float* Wv, float* bv)
{
    __shared__ float T[4096];
    __shared__ float ub[64];
    __shared__ float t3[64];
    int r = blockIdx.x, t = threadIdx.x;
    if (r < 2) {
        const float* w1 = r ? cm1 : lm1; const float* b1 = r ? cm1b : lm1b;
        const float* w2 = r ? cm2 : lm2; const float* b2 = r ? cm2b : lm2b;
        const float* w3 = r ? cm3 : lm3; const float* b3 = r ? cm3b : lm3b;
        float* W = r ? Wc : Wl;  float* bb = r ? bc : bl;
        for (int idx = t; idx < 4096; idx += 256) {
            int i = idx >> 6, j = idx & 63;
            float s = 0.f;
            for (int k = 0; k < 64; ++k) s += w1[i * 64 + k] * w2[k * 64 + j];
            T[idx] = s;
        }
        if (t < 64) {
            float s = 0.f;
            for (int k = 0; k < 64; ++k) s += b1[k] * w2[k * 64 + t];
            ub[t] = s + b2[t];
        }
        __syncthreads();
        for (int idx = t; idx < 4096; idx += 256) {
            int i = idx >> 6, j = idx & 63;
            float s = 0.f;
            for (int k = 0; k < 64; ++k) s += T[i * 64 + k] * w3[k * 64 + j];
            W[idx] = s;
        }
        if (t < 64) {
            float s = 0.f;
            for (int k = 0; k < 64; ++k) s += ub[k] * w3[k * 64 + t];
            bb[t] = s + b3[t];
        }
    } else {
        if (t < 64) {
            float s = 0.f;
            for (int j = 0; j < 64; ++j) s += lv2[t * 64 + j] * lv3[j];
            t3[t] = s;
            float s2 = 0.f;
            for (int k = 0; k < 64; ++k) s2 += lv1b[k] * lv2[k * 64 + t];
            ub[t] = s2 + lv2b[t];
        }
        __syncthreads();
        if (t < 64) {
            float s = 0.f;
            for (int k = 0; k < 64; ++k) s += lv1[t * 64 + k] * t3[k];
            Wv[t] = s;
        }
        if (t == 0) {
            float s = 0.f;
            for (int j = 0; j < 64; ++j) s += ub[j] * lv3[j];
            bv[0] = s + lv3b[0];
        }
    }
}

__global__ __launch_bounds__(256) void fold_k(
    const float* Wl, const float* bl, const float* Wc, const float* bc,
    const float* lwih, const float* lbih, const float* lbhh,
    const float* cwih, const float* cbih, const float* cbhh,
    float* Wfl, float* bfl, float* Bl, float* Wfc, float* Bc)
{
    int j = threadIdx.x;
    if (blockIdx.x == 0) {
        for (int i = 0; i < 64; ++i) {
            float s = 0.f;
            for (int m = 0; m < 64; ++m) s += Wc[i * 64 + m] * lwih[(64 + m) * 256 + j];
            Wfl[i * 256 + j] = s;
        }
        float s = 0.f;
        for (int m = 0; m < 64; ++m) s += bc[m] * lwih[(64 + m) * 256 + j];
        bfl[j] = s;
        Bl[j] = lbih[j] + lbhh[j];
    } else {
        for (int i = 0; i < 64; ++i) {
            float s = 0.f;
            for (int m = 0; m < 64; ++m) s += Wl[i * 64 + m] * cwih[m * 256 + j];
            Wfc[i * 256 + j] = s;
        }
        float s = 0.f;
        for (int m = 0; m < 64; ++m) s += bl[m] * cwih[m * 256 + j];
        Bc[j] = cbih[j] + cbhh[j] + 13.f * s;
    }
}

__global__ __launch_bounds__(256) void init_k(
    const float* x, const float* liw, const float* lib, const float* ciw, const float* cib,
    float* out0, float* outc)
{
    int t = blockIdx.x * 256 + threadIdx.x;
    if (t >= NN_ * 64) return;
    int node = t >> 6, j = t & 63;
    int b = node / NPG_;
    int i = node - b * NPG_;
    float x0 = x[node * 2 + 0], x1 = x[node * 2 + 1];
    if (i < NV2_) {
        int sp = (i < 400) ? 2 * i : 2 * (i - 400) + 1;
        out0[(size_t)(b * NV2_ + sp) * 64 + j] = x0 * liw[j] + x1 * liw[64 + j] + lib[j];
    } else {
        outc[(size_t)(b * NC_ + (i - NV2_)) * 64 + j] = x0 * ciw[j] + x1 * ciw[64 + j] + cib[j];
    }
}

__global__ __launch_bounds__(256) void econv_k(const int* ei, int* llits, int* cnt)
{
    int e = blockIdx.x * 256 + threadIdx.x;
    if (e >= NE_) return;
    int g = ei[e];
    int b = g / NPG_;
    int i = g - b * NPG_;
    int sp = (i < 400) ? 2 * i : 2 * (i - 400) + 1;
    int L = b * NV2_ + sp;
    llits[e] = L;
    atomicAdd(cnt + L, 1);
}

__global__ __launch_bounds__(1024) void scan_k(const int* cnt, int* rowptr, int* cursor)
{
    __shared__ int sums[1024];
    int t = threadIdx.x;
    int i0 = t * 13;
    int i1 = i0 + 13; if (i1 > NLIT_) i1 = NLIT_; if (i0 > NLIT_) i0 = NLIT_;
    int s = 0;
    for (int i = i0; i < i1; ++i) s += cnt[i];
    sums[t] = s;
    __syncthreads();
    for (int off = 1; off < 1024; off <<= 1) {
        int v = (t >= off) ? sums[t - off] : 0;
        __syncthreads();
        sums[t] += v;
        __syncthreads();
    }
    int run = sums[t] - s;
    for (int i = i0; i < i1; ++i) { rowptr[i] = run; cursor[i] = run; run += cnt[i]; }
    if (t == 1023) rowptr[NLIT_] = sums[1023];
}

__global__ __launch_bounds__(256) void fill_k(const int* llits, int* cursor, int* col)
{
    int e = blockIdx.x * 256 + threadIdx.x;
    if (e >= NE_) return;
    int pos = atomicAdd(cursor + llits[e], 1);
    col[pos] = e / KK_;
}

// ---------------- persistent fused kernel ----------------

struct KArgs {
    float* out_g; float* outc0; float* chg;
    const int* llits; const int* rowptr; const int* col;
    const float* Wfl; const float* bfl; const float* Bl;
    const float* Wfc; const float* Bc;
    const float* lwih; const float* lwhh; const float* cwhh;
    const float* Wv; const float* bv;
    float* vout; int* bar;
};

// RELEASE arrive: __syncthreads drains this block's stores, then t0 publishes
// with a release fetch_add (L2 dirty-line writeback to LLC; dirty set is just
// this step's comm data -> ~1us drain).
__device__ __forceinline__ void bar_arrive_rel(int* barg, int ph)
{
    __syncthreads();
    if (threadIdx.x == 0)
        __hip_atomic_fetch_add(barg + ph * PHSTR_, 1, __ATOMIC_RELEASE, __HIP_MEMORY_SCOPE_AGENT);
}

// ACQUIRE wait: relaxed spin, then one acquire load (cache inv) on success.
__device__ __forceinline__ void bar_wait_acq(int* barg, int ph, int target)
{
    if (threadIdx.x == 0) {
        while (__hip_atomic_load(barg + ph * PHSTR_, __ATOMIC_RELAXED, __HIP_MEMORY_SCOPE_AGENT) < target)
            __builtin_amdgcn_s_sleep(1);
        (void)__hip_atomic_load(barg + ph * PHSTR_, __ATOMIC_ACQUIRE, __HIP_MEMORY_SCOPE_AGENT);
    }
    __syncthreads();
}

// acc[g*4+q] += sum_k row[k] * W[k*WC + g*GS + uc4 + q]   (weights: LDS broadcast)
template<int WC, int GS>
__device__ __forceinline__ void gemm16(const float* __restrict__ row,
                                       const float* __restrict__ W,
                                       int uc4, float* acc)
{
    const float4* p = (const float4*)row;
#pragma unroll 4
    for (int k4 = 0; k4 < 16; ++k4) {
        float4 v = p[k4];
        const float* wk = W + (k4 * 4) * WC + uc4;
#pragma unroll
        for (int e = 0; e < 4; ++e) {
            float u = (e == 0) ? v.x : (e == 1) ? v.y : (e == 2) ? v.z : v.w;
            const float* wb = wk + e * WC;
#pragma unroll
            for (int g = 0; g < 4; ++g) {
                float4 w = *(const float4*)(wb + g * GS);
                acc[g * 4 + 0] = fmaf(u, w.x, acc[g * 4 + 0]);
                acc[g * 4 + 1] = fmaf(u, w.y, acc[g * 4 + 1]);
                acc[g * 4 + 2] = fmaf(u, w.z, acc[g * 4 + 2]);
                acc[g * 4 + 3] = fmaf(u, w.w, acc[g * 4 + 3]);
            }
        }
    }
}

__device__ __forceinline__ void cell4(const float* acc, float* c, float* h)
{
#pragma unroll
    for (int q = 0; q < 4; ++q) {
        float iv = sigmf(acc[q]);
        float fv = sigmf(acc[4 + q]);
        float gv = tanhf_(acc[8 + q]);
        float ov = sigmf(acc[12 + q]);
        float c2 = fv * c[q] + iv * gv;
        c[q] = c2;
        h[q] = ov * tanhf_(c2);
    }
}

__global__ __launch_bounds__(1024) void fused_k(KArgs a)
{
    extern __shared__ float sm[];
    const int tid = threadIdx.x;
    const int lane = tid & 63;
    const int wv = tid >> 6;                 // 0..15
    const int grp = blockIdx.x & 7;
    const int idx = blockIdx.x >> 3;         // role within group: 0..31
    int* barg = a.bar + grp * 48 * PHSTR_;

    if (idx < LITB_G) {
        // ======== literal block: <=128 rows x unit-half (32 units) ========
        const int rowgrp = idx >> 1;
        const int half = idx & 1;
        const int U0 = half * 32;
        const int OC = U0 ^ 32;            // other half's unit base
        const int Lb = grp * 1600 + rowgrp * 128;
        const int nrows = (rowgrp < 12) ? 128 : 64;
        float* wih_s = sm;                 // 64x128 (unit-half slice)
        float* whh_s = sm + 8192;
        float* wfl_s = sm + 16384;
        float* buf   = sm + 24576;         // 128 rows x stride 68 (full 64-col rows)
        float* hbuf  = sm + 33280;         // 128 rows x stride 36 (own 32-col piece)

        for (int i2 = tid; i2 < 8192; i2 += 1024) {
            int k = i2 >> 7, r = i2 & 127, gg = r >> 5, j = r & 31;
            int src = k * 256 + gg * 64 + U0 + j;
            wih_s[i2] = a.lwih[src];
            whh_s[i2] = a.lwhh[src];
            wfl_s[i2] = a.Wfl[src];
        }

        const int rh = wv >> 3, uc = wv & 7, uc4 = uc * 4;
        const int lr = rh * 64 + lane;
        const bool vrow = (lr < nrows);
        const int R = Lb + (vrow ? lr : 0);
        const int unit0 = U0 + uc4;
        const float degf = 1.f + (float)(a.rowptr[R + 1] - a.rowptr[R]);

        float bias[16];
#pragma unroll
        for (int g = 0; g < 4; ++g)
#pragma unroll
            for (int q = 0; q < 4; ++q)
                bias[g * 4 + q] = a.Bl[g * 64 + unit0 + q] + degf * a.bfl[g * 64 + unit0 + q];

        float lc4[4] = {0.f, 0.f, 0.f, 0.f};

        // thread-mapped piece indices: trow in [0,128), tc4 in {0,4,...,28}
        const int trow = tid >> 3;
        const int tc4 = (tid & 7) << 2;
        __syncthreads();

        for (int step = 0; step < STEPS_; ++step) {
            // slot1: assemble buf = out(step) full rows (own from hbuf, pair from out_g)
            if (trow < nrows) {
                const float* sp_ = a.out_g + (size_t)(Lb + trow) * 64;
                if (step == 0)
                    *(float4*)(buf + trow * 68 + U0 + tc4) = *(const float4*)(sp_ + U0 + tc4);
                else
                    *(float4*)(buf + trow * 68 + U0 + tc4) = *(float4*)(hbuf + trow * 36 + tc4);
                *(float4*)(buf + trow * 68 + OC + tc4) = *(const float4*)(sp_ + OC + tc4);
            }
            __syncthreads();
            float acc[16];
#pragma unroll
            for (int i = 0; i < 16; ++i) acc[i] = bias[i];
            gemm16<128, 32>(buf + (size_t)(lr ^ 1) * 68, wih_s, uc4, acc);     // out[flip] @ wih_top
            if (step) gemm16<128, 32>(buf + (size_t)lr * 68, whh_s, uc4, acc); // lh @ whh
            bar_wait_acq(barg, 2 * step, CLSB_G);   // chg(step) published by clause blocks
            // slot2: gather clause h, folded GEMM, cell
            for (int s8 = 0; s8 < 8; ++s8) {
                int srow = wv * 8 + s8;
                if (srow >= nrows) continue;
                int l = Lb + srow;
                int e = a.rowptr[l], eE = a.rowptr[l + 1];
                float v = buf[srow * 68 + lane];
                for (; e + 8 <= eE; e += 8) {
                    float t0 = a.chg[(size_t)a.col[e    ] * 64 + lane];
                    float t1 = a.chg[(size_t)a.col[e + 1] * 64 + lane];
                    float t2 = a.chg[(size_t)a.col[e + 2] * 64 + lane];
                    float t3 = a.chg[(size_t)a.col[e + 3] * 64 + lane];
                    float t4 = a.chg[(size_t)a.col[e + 4] * 64 + lane];
                    float t5 = a.chg[(size_t)a.col[e + 5] * 64 + lane];
                    float t6 = a.chg[(size_t)a.col[e + 6] * 64 + lane];
                    float t7 = a.chg[(size_t)a.col[e + 7] * 64 + lane];
                    v += ((t0 + t1) + (t2 + t3)) + ((t4 + t5) + (t6 + t7));
                }
                for (; e + 4 <= eE; e += 4) {
                    float t0 = a.chg[(size_t)a.col[e    ] * 64 + lane];
                    float t1 = a.chg[(size_t)a.col[e + 1] * 64 + lane];
                    float t2 = a.chg[(size_t)a.col[e + 2] * 64 + lane];
                    float t3 = a.chg[(size_t)a.col[e + 3] * 64 + lane];
                    v += t0 + t1 + t2 + t3;
                }
                for (; e < eE; ++e) v += a.chg[(size_t)a.col[e] * 64 + lane];
                buf[srow * 68 + lane] = v;
            }
            __syncthreads();
            gemm16<128, 32>(buf + (size_t)lr * 68, wfl_s, uc4, acc);
            float h2[4];
            cell4(acc, lc4, h2);
            // stage h into hbuf, then full-line-dense cached store of own piece
#pragma unroll
            for (int q = 0; q < 4; ++q) hbuf[lr * 36 + uc4 + q] = h2[q];
            __syncthreads();
            if (trow < nrows)
                *(float4*)(a.out_g + (size_t)(Lb + trow) * 64 + U0 + tc4) =
                    *(float4*)(hbuf + trow * 36 + tc4);
            if (step < STEPS_ - 1) {
                bar_arrive_rel(barg, 2 * step + 1);             // publish out_g (release)
                bar_wait_acq(barg, 2 * step + 1, LITB_G);       // all lit published
            } else {
                // vote epilogue
                float p = h2[0] * a.Wv[unit0] + h2[1] * a.Wv[unit0 + 1]
                        + h2[2] * a.Wv[unit0 + 2] + h2[3] * a.Wv[unit0 + 3];
                __syncthreads();
                if (vrow) buf[lr * 8 + uc] = p;
                __syncthreads();
                if (uc == 0 && vrow) {
                    float v = (half == 0) ? a.bv[0] : 0.f;
#pragma unroll
                    for (int w = 0; w < 8; ++w) v += buf[lr * 8 + w];
                    int b = R / NV2_;
                    int pos = R - b * NV2_;
                    int pi = (pos >> 1) + (pos & 1) * 400;   // undo pair-interleave
                    atomicAdd(a.vout + b * NPG_ + pi, v);
                }
            }
        }
    } else {
        // ======== clause block: ~147 rows (3 subgroups of <=64), full 64 units ========
        const int ci = idx - LITB_G;                         // 0..5
        const int rows = (ci < 4) ? 147 : 146;               // 880 rows per group
        const int c0 = grp * 880 + ci * 147 - ((ci > 4) ? (ci - 4) : 0);
        float* wfc_s  = sm;             // 64x256
        float* cwhh_s = sm + 16384;     // 64x256
        float* LM     = sm + 32768;     // 64 rows x stride 68
        for (int i2 = tid; i2 < 16384; i2 += 1024) {
            wfc_s[i2]  = a.Wfc[i2];
            cwhh_s[i2] = a.cwhh[i2];
        }
        const int u0 = wv * 4;          // this wave's 4 units
        float bc16[16];
#pragma unroll
        for (int g = 0; g < 4; ++g)
#pragma unroll
            for (int q = 0; q < 4; ++q) bc16[g * 4 + q] = a.Bc[g * 64 + u0 + q];
        float cc_r[3][4] = {};
        float acc2[3][16] = {};
        // thread-mapped store indices: srw in [0,64), sc4 in {0,4,...,60}
        const int srw = tid >> 4;
        const int sc4 = (tid & 15) << 2;
        __syncthreads();

        for (int step = 0; step < STEPS_; ++step) {
            float ch_r[3][4];
#pragma unroll 1
            for (int sg = 0; sg < 3; ++sg) {
                const int r0 = sg * 64;
                const int cnt = (rows - r0 < 64) ? (rows - r0) : 64;
                // gather lmsg = clause_out + sum of 12 literal outs
                for (int s4 = 0; s4 < 4; ++s4) {
                    int srow = wv * 4 + s4;
                    if (srow < cnt) {
                        int c = c0 + r0 + srow;
                        float v = step ? a.chg[(size_t)c * 64 + lane]
                                       : a.outc0[(size_t)c * 64 + lane];
                        const int* lp = a.llits + c * KK_;
                        float t0 = a.out_g[(size_t)lp[0] * 64 + lane];
                        float t1 = a.out_g[(size_t)lp[1] * 64 + lane];
                        float t2 = a.out_g[(size_t)lp[2] * 64 + lane];
                        float t3 = a.out_g[(size_t)lp[3] * 64 + lane];
                        float t4 = a.out_g[(size_t)lp[4] * 64 + lane];
                        float t5 = a.out_g[(size_t)lp[5] * 64 + lane];
                        float t6 = a.out_g[(size_t)lp[6] * 64 + lane];
                        float t7 = a.out_g[(size_t)lp[7] * 64 + lane];
                        float t8 = a.out_g[(size_t)lp[8] * 64 + lane];
                        float t9 = a.out_g[(size_t)lp[9] * 64 + lane];
                        float ta = a.out_g[(size_t)lp[10] * 64 + lane];
                        float tb = a.out_g[(size_t)lp[11] * 64 + lane];
                        v += t0 + t1 + t2 + t3 + t4 + t5 + t6 + t7 + t8 + t9 + ta + tb;
                        LM[srow * 68 + lane] = v;
                    }
                }
                __syncthreads();
                float acc[16];
#pragma unroll
                for (int i = 0; i < 16; ++i) acc[i] = bc16[i] + acc2[sg][i];
                gemm16<256, 64>(LM + (size_t)lane * 68, wfc_s, u0, acc);
                cell4(acc, cc_r[sg], ch_r[sg]);
                __syncthreads();    // all LM gather reads done
                // stage full ch rows into LM, then full-line-dense cached store
#pragma unroll
                for (int q = 0; q < 4; ++q) LM[lane * 68 + u0 + q] = ch_r[sg][q];
                __syncthreads();
                if (srw < cnt)
                    *(float4*)(a.chg + (size_t)(c0 + r0 + srw) * 64 + sc4) =
                        *(float4*)(LM + srw * 68 + sc4);
                __syncthreads();    // LM free for next subgroup's gather
            }
            bar_arrive_rel(barg, 2 * step);    // publish chg (release); clause skips S2 wait
            if (step < STEPS_ - 1) {
                // precompute ch(step) @ cwhh for next step while lit does slot2
#pragma unroll 1
                for (int sg = 0; sg < 3; ++sg) {
                    *(float4*)(LM + (size_t)lane * 68 + u0) =
                        make_float4(ch_r[sg][0], ch_r[sg][1], ch_r[sg][2], ch_r[sg][3]);
                    __syncthreads();
#pragma unroll
                    for (int i = 0; i < 16; ++i) acc2[sg][i] = 0.f;
                    gemm16<256, 64>(LM + (size_t)lane * 68, cwhh_s, u0, acc2[sg]);
                    __syncthreads();
                }
                bar_wait_acq(barg, 2 * step + 1, LITB_G);   // out_g(step+1) published by lit
            }
        }
    }
}

// ---------------- host ----------------

extern "C" void kernel_launch(void* const* d_in, const int* in_sizes, int n_in,
                              void* d_out, int out_size, void* d_ws, size_t ws_size,
                              hipStream_t stream)
{
    (void)in_sizes; (void)n_in; (void)out_size; (void)ws_size;
    const float* x    = (const float*)d_in[0];
    const int*   ei   = (const int*)d_in[2];
    const float* liw  = (const float*)d_in[4];
    const float* lib  = (const float*)d_in[5];
    const float* ciw  = (const float*)d_in[6];
    const float* cib  = (const float*)d_in[7];
    const float* lm1  = (const float*)d_in[8];
    const float* lm1b = (const float*)d_in[9];
    const float* lm2  = (const float*)d_in[10];
    const float* lm2b = (const float*)d_in[11];
    const float* lm3  = (const float*)d_in[12];
    const float* lm3b = (const float*)d_in[13];
    const float* cm1  = (const float*)d_in[14];
    const float* cm1b = (const float*)d_in[15];
    const float* cm2  = (const float*)d_in[16];
    const float* cm2b = (const float*)d_in[17];
    const float* cm3  = (const float*)d_in[18];
    const float* cm3b = (const float*)d_in[19];
    const float* lu_wih = (const float*)d_in[20];
    const float* lu_whh = (const float*)d_in[21];
    const float* lu_bih = (const float*)d_in[22];
    const float* lu_bhh = (const float*)d_in[23];
    const float* cu_wih = (const float*)d_in[24];
    const float* cu_whh = (const float*)d_in[25];
    const float* cu_bih = (const float*)d_in[26];
    const float* cu_bhh = (const float*)d_in[27];
    const float* lv1  = (const float*)d_in[28];
    const float* lv1b = (const float*)d_in[29];
    const float* lv2  = (const float*)d_in[30];
    const float* lv2b = (const float*)d_in[31];
    const float* lv3  = (const float*)d_in[32];
    const float* lv3b = (const float*)d_in[33];

    float* F = (float*)d_ws;
    size_t o = 0;
    auto A = [&](size_t n) { float* p = F + o; o += n; return p; };
    float* out_g = A((size_t)NLIT_ * 64);
    float* outc0 = A((size_t)NCLS_ * 64);
    float* chg   = A((size_t)NCLS_ * 64);
    float* Wl    = A(4096);
    float* Wc    = A(4096);
    float* bl    = A(64);
    float* bc    = A(64);
    float* Wv    = A(64);
    float* bv    = A(16);
    float* Wfl   = A(64 * 256);
    float* bfl   = A(256);
    float* Bl    = A(256);
    float* Wfc   = A(64 * 256);
    float* Bc    = A(256);
    int* I = (int*)(F + o);
    int* llits  = I; I += NE_;
    int* rowptr = I; I += 12804;
    int* cursor = I; I += NLIT_;
    int* colA   = I; I += NE_;
    int* cnt    = I; I += NLIT_;
    int* bar    = I; I += GRP_ * 48 * PHSTR_;

    hipMemsetAsync(cnt, 0, NLIT_ * sizeof(int), stream);
    hipMemsetAsync(bar, 0, GRP_ * 48 * PHSTR_ * sizeof(int), stream);
    hipMemsetAsync(d_out, 0, (size_t)NN_ * sizeof(float), stream);

    collapse_k<<<3, 256, 0, stream>>>(lm1, lm1b, lm2, lm2b, lm3, lm3b,
                                      cm1, cm1b, cm2, cm2b, cm3, cm3b,
                                      lv1, lv1b, lv2, lv2b, lv3, lv3b,
                                      Wl, bl, Wc, bc, Wv, bv);
    fold_k<<<2, 256, 0, stream>>>(Wl, bl, Wc, bc,
                                  lu_wih, lu_bih, lu_bhh,
                                  cu_wih, cu_bih, cu_bhh,
                                  Wfl, bfl, Bl, Wfc, Bc);
    init_k<<<(NN_ * 64 + 255) / 256, 256, 0, stream>>>(x, liw, lib, ciw, cib, out_g, outc0);
    econv_k<<<NE_ / 256, 256, 0, stream>>>(ei, llits, cnt);
    scan_k<<<1, 1024, 0, stream>>>(cnt, rowptr, cursor);
    fill_k<<<NE_ / 256, 256, 0, stream>>>(llits, cursor, colA);

    KArgs ka;
    ka.out_g = out_g; ka.outc0 = outc0; ka.chg = chg;
    ka.llits = llits; ka.rowptr = rowptr; ka.col = colA;
    ka.Wfl = Wfl; ka.bfl = bfl; ka.Bl = Bl; ka.Wfc = Wfc; ka.Bc = Bc;
    ka.lwih = lu_wih; ka.lwhh = lu_whh; ka.cwhh = cu_whh;
    ka.Wv = Wv; ka.bv = bv;
    ka.vout = (float*)d_out;
    ka.bar = bar;

    void* params[] = { &ka };
    hipError_t err = hipLaunchCooperativeKernel((void*)fused_k, dim3(NBLK_), dim3(1024),
                                                params, SMEM_BYTES, stream);
    if (err != hipSuccess) {
        fused_k<<<NBLK_, 1024, SMEM_BYTES, stream>>>(ka);
    }
}